// Round 3
// baseline (190.032 us; speedup 1.0000x reference)
//
#include <hip/hip_runtime.h>
#include <math.h>
#include <stdint.h>

#define D_MODEL 2048
#define NEXP    64
#define TOKENS  32768
#define BM      64
#define BK      64
#define NT      256
#define NCHUNK  (D_MODEL / BK)   // 32
#define TIE_THR 1e-3f            // split-bf16 logit err ~5e-6; 200x margin

typedef __attribute__((ext_vector_type(8))) short short8;   // 8 bf16 = 4 VGPR (MFMA A/B frag)
typedef __attribute__((ext_vector_type(4))) short short4v;  // 8B packed bf16 quad
typedef __attribute__((ext_vector_type(4))) float f32x4;    // MFMA C/D frag

__device__ __forceinline__ unsigned short bf16r(float v) {  // RTNE fp32->bf16
    uint32_t u = __float_as_uint(v);
    return (unsigned short)((u + 0x7fffu + ((u >> 16) & 1u)) >> 16);
}
__device__ __forceinline__ float bf2f(unsigned short h) {
    return __uint_as_float(((uint32_t)h) << 16);
}

// LDS layout (dbuf): buf b at byte 32768*b; within buf: Xh(+0) Xl(+8192) Wh(+16384) Wl(+24576)
// each tile [64 rows][64 bf16] = 128 B/row, XOR-swizzled at 16B granule: slot16 ^= (row&7).

// Load chunk c: 8 coalesced float4 per thread (x + W tiles, read-once x).
#define LOAD_CHUNK(c)                                                     \
    _Pragma("unroll")                                                     \
    for (int j = 0; j < 4; ++j) {                                         \
        rx[j] = *(const float4*)(xp[j] + (size_t)(c) * BK);               \
        rw[j] = *(const float4*)(wp[j] + (size_t)(c) * BK);               \
    }

// Convert staged fp32 -> bf16 hi/lo pairs and ds_write_b64 into buffer b.
#define CVT_WRITE(b)                                                      \
    do {                                                                  \
        char* base_ = smem + 32768 * (b);                                 \
        _Pragma("unroll")                                                 \
        for (int j = 0; j < 4; ++j) {                                     \
            short4v h_, l_;                                               \
            unsigned short t_;                                            \
            t_ = bf16r(rx[j].x); h_.x = (short)t_; l_.x = (short)bf16r(rx[j].x - bf2f(t_)); \
            t_ = bf16r(rx[j].y); h_.y = (short)t_; l_.y = (short)bf16r(rx[j].y - bf2f(t_)); \
            t_ = bf16r(rx[j].z); h_.z = (short)t_; l_.z = (short)bf16r(rx[j].z - bf2f(t_)); \
            t_ = bf16r(rx[j].w); h_.w = (short)t_; l_.w = (short)bf16r(rx[j].w - bf2f(t_)); \
            *(short4v*)(base_ +     0 + wr_off[j]) = h_;                  \
            *(short4v*)(base_ +  8192 + wr_off[j]) = l_;                  \
            t_ = bf16r(rw[j].x); h_.x = (short)t_; l_.x = (short)bf16r(rw[j].x - bf2f(t_)); \
            t_ = bf16r(rw[j].y); h_.y = (short)t_; l_.y = (short)bf16r(rw[j].y - bf2f(t_)); \
            t_ = bf16r(rw[j].z); h_.z = (short)t_; l_.z = (short)bf16r(rw[j].z - bf2f(t_)); \
            t_ = bf16r(rw[j].w); h_.w = (short)t_; l_.w = (short)bf16r(rw[j].w - bf2f(t_)); \
            *(short4v*)(base_ + 16384 + wr_off[j]) = h_;                  \
            *(short4v*)(base_ + 24576 + wr_off[j]) = l_;                  \
        }                                                                 \
    } while (0)

// 4-term split MFMA over buffer b: acc += (Xh+Xl)(Wh+Wl)^T, 32 MFMA/wave/chunk.
#define MFMA_BUF(b)                                                       \
    do {                                                                  \
        const char* base_ = smem + 32768 * (b);                           \
        _Pragma("unroll")                                                 \
        for (int st = 0; st < 2; ++st) {                                  \
            short8 ah_ = *(const short8*)(base_ +    0 + a_off[st]);      \
            short8 al_ = *(const short8*)(base_ + 8192 + a_off[st]);      \
            _Pragma("unroll")                                             \
            for (int n = 0; n < 4; ++n) {                                 \
                short8 bh_ = *(const short8*)(base_ + 16384 + b_off[n][st]); \
                short8 bl_ = *(const short8*)(base_ + 24576 + b_off[n][st]); \
                acc[n] = __builtin_amdgcn_mfma_f32_16x16x32_bf16(ah_, bh_, acc[n], 0, 0, 0); \
                acc[n] = __builtin_amdgcn_mfma_f32_16x16x32_bf16(al_, bh_, acc[n], 0, 0, 0); \
                acc[n] = __builtin_amdgcn_mfma_f32_16x16x32_bf16(ah_, bl_, acc[n], 0, 0, 0); \
                acc[n] = __builtin_amdgcn_mfma_f32_16x16x32_bf16(al_, bl_, acc[n], 0, 0, 0); \
            }                                                             \
        }                                                                 \
    } while (0)

__global__ __launch_bounds__(NT, 2)
void router_kernel(const float* __restrict__ x, const float* __restrict__ W,
                   float* __restrict__ out)
{
    __shared__ char smem[65536];
    __shared__ int  flaglist[BM];
    __shared__ int  nflag;

    const int tid  = threadIdx.x;
    const int lane = tid & 63;
    const int wave = tid >> 6;            // 0..3: token stripe 16*wave
    const int row0 = blockIdx.x * BM;

    // ---- staging addresses: f = tid + 256j -> row = (tid>>4)+16j, slot = tid&15 ----
    const int tr0 = tid >> 4;
    const int sl  = tid & 15;
    const float* xp[4];
    const float* wp[4];
    int wr_off[4];
#pragma unroll
    for (int j = 0; j < 4; ++j) {
        const int r = tr0 + 16 * j;
        xp[j] = x + (size_t)(row0 + r) * D_MODEL + 4 * sl;
        wp[j] = W + (size_t)r * D_MODEL + 4 * sl;
        wr_off[j] = r * 128 + 16 * ((sl >> 1) ^ (r & 7)) + 8 * (sl & 1);
    }

    // ---- fragment read offsets (swizzled) ----
    const int fr = lane & 15;             // frag row-within-16 / D col
    const int fg = lane >> 4;             // k-group 0..3
    int a_off[2], b_off[4][2];
#pragma unroll
    for (int st = 0; st < 2; ++st) {
        const int ar = 16 * wave + fr;
        a_off[st] = ar * 128 + 16 * (((st << 2) + fg) ^ (ar & 7));
#pragma unroll
        for (int n = 0; n < 4; ++n) {
            const int br = 16 * n + fr;
            b_off[n][st] = br * 128 + 16 * (((st << 2) + fg) ^ (br & 7));
        }
    }

    f32x4 acc[4];
#pragma unroll
    for (int n = 0; n < 4; ++n) acc[n] = (f32x4){0.f, 0.f, 0.f, 0.f};

    float4 rx[4], rw[4];
    LOAD_CHUNK(0);
    CVT_WRITE(0);
    __syncthreads();

    for (int c = 0; c < NCHUNK; ++c) {
        const int buf = c & 1;
        if (c + 1 < NCHUNK) { LOAD_CHUNK(c + 1); }   // issue early; consumed after barrier A
        MFMA_BUF(buf);
        __syncthreads();                              // A: all reads of buf^1 (prev iter) long done; writers may go
        if (c + 1 < NCHUNK) { CVT_WRITE(buf ^ 1); }
        __syncthreads();                              // B: buf^1 ready for next iter
    }

    // ---- epilogue: dump logits [64][stride 66] into (dead) buf0 region ----
    float* logits = (float*)smem;
#pragma unroll
    for (int n = 0; n < 4; ++n)
#pragma unroll
        for (int r = 0; r < 4; ++r)
            logits[(16 * wave + 4 * fg + r) * 66 + 16 * n + fr] = acc[n][r];
    if (tid == 0) nflag = 0;
    __syncthreads();

    // top-3 scan per token (threads 0..63), flag near-ties for exact recompute
    float m1 = -INFINITY, m2 = -INFINITY, m3 = -INFINITY;
    int   i1 = 0, i2 = 0;
    bool  tie = false;
    if (tid < BM) {
#pragma unroll 8
        for (int e = 0; e < NEXP; ++e) {
            const float v = logits[tid * 66 + e];
            if (v > m1)      { m3 = m2; m2 = m1; i2 = i1; m1 = v; i1 = e; }
            else if (v > m2) { m3 = m2; m2 = v; i2 = e; }
            else if (v > m3) { m3 = v; }
        }
        tie = (m1 - m2 < TIE_THR) || (m2 - m3 < TIE_THR);
        if (tie) { const int p = atomicAdd(&nflag, 1); flaglist[p] = tid; }
    }
    __syncthreads();

    // ---- exact fp32 cleanup for flagged tokens (rare: ~0.3/block) ----
    const int nf = nflag;
    float* partial = (float*)(smem + 32768);   // [4][64] in dead buf1 region
    for (int f = 0; f < nf; ++f) {
        const int t = flaglist[f];
        const float* xr = x + (size_t)(row0 + t) * D_MODEL + 512 * wave;
        const float* wrow = W + (size_t)lane * D_MODEL + 512 * wave;
        float ps = 0.f;
        for (int k = 0; k < 512; k += 4) {
            const float4 xv = *(const float4*)(xr + k);
            const float4 wv = *(const float4*)(wrow + k);
            ps = fmaf(xv.x, wv.x, ps); ps = fmaf(xv.y, wv.y, ps);
            ps = fmaf(xv.z, wv.z, ps); ps = fmaf(xv.w, wv.w, ps);
        }
        partial[wave * 64 + lane] = ps;
        __syncthreads();
        if (tid < NEXP)
            logits[t * 66 + tid] = (partial[tid] + partial[64 + tid]) +
                                   (partial[128 + tid] + partial[192 + tid]);
        __syncthreads();
    }

    if (tid < BM) {
        if (tie) {   // rescan the exact row
            m1 = -INFINITY; m2 = -INFINITY; i1 = 0; i2 = 0;
#pragma unroll 8
            for (int e = 0; e < NEXP; ++e) {
                const float v = logits[tid * 66 + e];
                if (v > m1)      { m2 = m1; i2 = i1; m1 = v; i1 = e; }
                else if (v > m2) { m2 = v; i2 = e; }
            }
        }
        const float ex = expf(m2 - m1);        // renormalized top-2 softmax
        const float g1 = 1.0f / (1.0f + ex);
        const float g2 = ex * g1;
        const int row = row0 + tid;
        out[(size_t)row * 2 + 0] = g1;
        out[(size_t)row * 2 + 1] = g2;
        out[(size_t)TOKENS * 2 + (size_t)row * 2 + 0] = (float)i1;
        out[(size_t)TOKENS * 2 + (size_t)row * 2 + 1] = (float)i2;
    }
}

extern "C" void kernel_launch(void* const* d_in, const int* in_sizes, int n_in,
                              void* d_out, int out_size, void* d_ws, size_t ws_size,
                              hipStream_t stream) {
    const float* x = (const float*)d_in[0];
    const float* W = (const float*)d_in[1];
    float* out = (float*)d_out;
    router_kernel<<<TOKENS / BM, NT, 0, stream>>>(x, W, out);
}

// Round 4
// 179.028 us; speedup vs baseline: 1.0615x; 1.0615x over previous
//
#include <hip/hip_runtime.h>
#include <math.h>
#include <stdint.h>

#define D_MODEL 2048
#define NEXP    64
#define TOKENS  32768
#define BM      64
#define BK      64
#define NT      256
#define NCHUNK  (D_MODEL / BK)   // 32
#define TIE_THR 1e-3f            // 3-term split logit err ~4e-5; 25x margin
#define LSTRIDE 66

typedef __attribute__((ext_vector_type(8))) short short8;  // MFMA A/B frag (8 bf16)
typedef __attribute__((ext_vector_type(4))) float f32x4;   // MFMA C/D frag
typedef __attribute__((ext_vector_type(4))) int   i32x4;

typedef __attribute__((address_space(3))) uint32_t       lds_u32_t;
typedef const __attribute__((address_space(1))) uint32_t gbl_u32_t;

// Stage one 64x64 fp32 chunk of x and W into LDS buffer b (r2-proven pattern).
// 1KB packet per global_load_lds; source col pre-swizzled (quad ^ (row&7)) so
// the linear LDS image is bank-swizzled; frag reads undo the XOR.
#define STAGE(c, b)                                                            \
    _Pragma("unroll")                                                          \
    for (int g = 0; g < 4; ++g) {                                              \
        const int G_ = 4 * wave + g;                                           \
        __builtin_amdgcn_global_load_lds((gbl_u32_t*)(xsrc[g] + (size_t)(c) * BK), \
                                         (lds_u32_t*)&xs[b][4 * G_][0], 16, 0, 0); \
        __builtin_amdgcn_global_load_lds((gbl_u32_t*)(wsrc[g] + (size_t)(c) * BK), \
                                         (lds_u32_t*)&ws[b][4 * G_][0], 16, 0, 0); \
    }

// Split a pair of fp32 into packed bf16 hi (RTZ) and lo words.
// hi = top 16 bits (truncation); lo = bf16_rtz(f - hi). |f-(hi+lo)| <= 2^-15|f|.
__device__ __forceinline__ void split2(float f0, float f1, uint32_t& hw, uint32_t& lw)
{
    const uint32_t u0 = __float_as_uint(f0), u1 = __float_as_uint(f1);
    const uint32_t a0 = u0 & 0xffff0000u,  a1 = u1 & 0xffff0000u;
    hw = a1 | (u0 >> 16);
    const float l0 = f0 - __uint_as_float(a0);
    const float l1 = f1 - __uint_as_float(a1);
    lw = (__float_as_uint(l1) & 0xffff0000u) | (__float_as_uint(l0) >> 16);
}

// Read one fp32 k-octet (two swizzled b128 quads) and split to hi/lo bf16 frags.
__device__ __forceinline__ void ldsplit(const char* p0, const char* p1,
                                        short8& h8, short8& l8)
{
    const float4 qa = *(const float4*)p0;   // k-quad q0   (k+0..3)
    const float4 qb = *(const float4*)p1;   // k-quad q0+1 (k+4..7)
    i32x4 hv, lv;
    uint32_t hw, lw;
    split2(qa.x, qa.y, hw, lw); hv[0] = (int)hw; lv[0] = (int)lw;
    split2(qa.z, qa.w, hw, lw); hv[1] = (int)hw; lv[1] = (int)lw;
    split2(qb.x, qb.y, hw, lw); hv[2] = (int)hw; lv[2] = (int)lw;
    split2(qb.z, qb.w, hw, lw); hv[3] = (int)hw; lv[3] = (int)lw;
    h8 = *(short8*)&hv;
    l8 = *(short8*)&lv;
}

__global__ __launch_bounds__(NT, 2)
void router_kernel(const float* __restrict__ x, const float* __restrict__ W,
                   float* __restrict__ out)
{
    __shared__ float xs[2][BM][BK];     // 32 KB fp32 token tiles
    __shared__ float ws[2][NEXP][BK];   // 32 KB fp32 expert tiles
    __shared__ int   flaglist[BM];
    __shared__ int   nflag;

    const int tid  = threadIdx.x;
    const int lane = tid & 63;
    const int wave = tid >> 6;
    const int row0 = blockIdx.x * BM;

    // ---- staging sources (pre-swizzled, r2 pattern) ----
    const int lrow  = lane >> 4;
    const int lslot = lane & 15;
    const float* xsrc[4];
    const float* wsrc[4];
#pragma unroll
    for (int g = 0; g < 4; ++g) {
        const int r   = 16 * wave + 4 * g + lrow;
        const int col = 4 * (lslot ^ (r & 7));
        xsrc[g] = x + (size_t)(row0 + r) * D_MODEL + col;
        wsrc[g] = W + (size_t)r * D_MODEL + col;
    }

    // ---- fragment geometry: wave covers m-tiles {mt0,mt0+1} x n-tiles {nt0,nt0+1} ----
    const int fr  = lane & 15;            // frag row within 16
    const int h   = lane >> 4;            // k-octet group
    const int sw  = 16 * (fr & 7);        // byte swizzle key (row&7 == fr&7 for all tiles)
    const int t0b = (32 * h) ^ sw;        // s=0 quad byte offset (within row)
    const int mt0 = 2 * (wave & 1);
    const int nt0 = 2 * (wave >> 1);
    const int rowA[2] = { (16 * (mt0 + 0) + fr) * 256, (16 * (mt0 + 1) + fr) * 256 };
    const int rowB[2] = { (16 * (nt0 + 0) + fr) * 256, (16 * (nt0 + 1) + fr) * 256 };

    f32x4 acc[2][2] = {};

    STAGE(0, 0);
    __syncthreads();

    for (int c = 0; c < NCHUNK; ++c) {
        const int buf = c & 1;
        if (c + 1 < NCHUNK) STAGE(c + 1, buf ^ 1);   // lands before next barrier
        const char* xb = (const char*)&xs[buf][0][0];
        const char* wb = (const char*)&ws[buf][0][0];
#pragma unroll
        for (int s = 0; s < 2; ++s) {                 // two k-steps of 32
            const int off0 = 128 * s + t0b;
            short8 ah[2], al[2], bh[2], bl[2];
#pragma unroll
            for (int mi = 0; mi < 2; ++mi)
                ldsplit(xb + rowA[mi] + off0, xb + rowA[mi] + (off0 ^ 16), ah[mi], al[mi]);
#pragma unroll
            for (int ni = 0; ni < 2; ++ni)
                ldsplit(wb + rowB[ni] + off0, wb + rowB[ni] + (off0 ^ 16), bh[ni], bl[ni]);
#pragma unroll
            for (int mi = 0; mi < 2; ++mi)
#pragma unroll
                for (int ni = 0; ni < 2; ++ni) {
                    acc[mi][ni] = __builtin_amdgcn_mfma_f32_16x16x32_bf16(ah[mi], bh[ni], acc[mi][ni], 0, 0, 0);
                    acc[mi][ni] = __builtin_amdgcn_mfma_f32_16x16x32_bf16(al[mi], bh[ni], acc[mi][ni], 0, 0, 0);
                    acc[mi][ni] = __builtin_amdgcn_mfma_f32_16x16x32_bf16(ah[mi], bl[ni], acc[mi][ni], 0, 0, 0);
                }
        }
        __syncthreads();
    }

    // ---- epilogue: logits into dead xs region ----
    float* logits = (float*)&xs[0][0][0];   // 64*66*4 = 16.9 KB < 32 KB
#pragma unroll
    for (int mi = 0; mi < 2; ++mi)
#pragma unroll
        for (int ni = 0; ni < 2; ++ni)
#pragma unroll
            for (int r = 0; r < 4; ++r)
                logits[(16 * (mt0 + mi) + 4 * h + r) * LSTRIDE + 16 * (nt0 + ni) + fr] =
                    acc[mi][ni][r];
    if (tid == 0) nflag = 0;
    __syncthreads();

    // ---- top-3 scan, flag near-ties ----
    float m1 = -INFINITY, m2 = -INFINITY, m3 = -INFINITY;
    int   i1 = 0, i2 = 0;
    bool  tie = false;
    if (tid < BM) {
#pragma unroll 8
        for (int e = 0; e < NEXP; ++e) {
            const float v = logits[tid * LSTRIDE + e];
            if (v > m1)      { m3 = m2; m2 = m1; i2 = i1; m1 = v; i1 = e; }
            else if (v > m2) { m3 = m2; m2 = v; i2 = e; }
            else if (v > m3) { m3 = v; }
        }
        tie = (m1 - m2 < TIE_THR) || (m2 - m3 < TIE_THR);
        if (tie) { const int p = atomicAdd(&nflag, 1); flaglist[p] = tid; }
    }
    __syncthreads();

    // ---- exact fp32 cleanup for flagged tokens (~1%) ----
    const int nf = nflag;
    float* partial = (float*)&ws[0][0][0];   // dead region
    for (int f = 0; f < nf; ++f) {
        const int t = flaglist[f];
        const float* xr   = x + (size_t)(row0 + t) * D_MODEL + 512 * wave;
        const float* wrow = W + (size_t)lane * D_MODEL + 512 * wave;
        float ps = 0.f;
        for (int k = 0; k < 512; k += 4) {
            const float4 xv = *(const float4*)(xr + k);
            const float4 wv = *(const float4*)(wrow + k);
            ps = fmaf(xv.x, wv.x, ps); ps = fmaf(xv.y, wv.y, ps);
            ps = fmaf(xv.z, wv.z, ps); ps = fmaf(xv.w, wv.w, ps);
        }
        partial[wave * 64 + lane] = ps;
        __syncthreads();
        if (tid < NEXP)
            logits[t * LSTRIDE + tid] = (partial[tid] + partial[64 + tid]) +
                                        (partial[128 + tid] + partial[192 + tid]);
        __syncthreads();
    }

    if (tid < BM) {
        if (tie) {   // rescan exact row
            m1 = -INFINITY; m2 = -INFINITY; i1 = 0; i2 = 0;
#pragma unroll 8
            for (int e = 0; e < NEXP; ++e) {
                const float v = logits[tid * LSTRIDE + e];
                if (v > m1)      { m2 = m1; i2 = i1; m1 = v; i1 = e; }
                else if (v > m2) { m2 = v; i2 = e; }
            }
        }
        const float ex = expf(m2 - m1);      // renormalized top-2 softmax
        const float g1 = 1.0f / (1.0f + ex);
        const float g2 = ex * g1;
        const int row = row0 + tid;
        out[(size_t)row * 2 + 0] = g1;
        out[(size_t)row * 2 + 1] = g2;
        out[(size_t)TOKENS * 2 + (size_t)row * 2 + 0] = (float)i1;
        out[(size_t)TOKENS * 2 + (size_t)row * 2 + 1] = (float)i2;
    }
}

extern "C" void kernel_launch(void* const* d_in, const int* in_sizes, int n_in,
                              void* d_out, int out_size, void* d_ws, size_t ws_size,
                              hipStream_t stream) {
    const float* x = (const float*)d_in[0];
    const float* W = (const float*)d_in[1];
    float* out = (float*)d_out;
    router_kernel<<<TOKENS / BM, NT, 0, stream>>>(x, W, out);
}